// Round 13
// baseline (218.323 us; speedup 1.0000x reference)
//
#include <hip/hip_runtime.h>
#include <cstdint>
#include <cstddef>

#define THETA 1.2f
#define XI 0.3f
#define BDIM 8192
#define DDIM 512
#define NUNITS 4160        // 64-row x 128-col upper-tri units: sum_m 2*(64-m) = 4160
// upper-triangle-with-diagonal pair count: B*(B+1)/2
#define NPAIRS_UP (((double)BDIM * (double)(BDIM + 1)) * 0.5)

typedef float f32x4 __attribute__((ext_vector_type(4)));
typedef int i32x8 __attribute__((ext_vector_type(8)));

// ---------------------------------------------------------------------------
// Fragment-major ("tiled") fp8 layout (verified r6-r11):
//   frag F = (row/16)*4 + (kbyte/128)   -- 16 rows x 128 B of K = one MFMA frag
//   blob of 2048 B at F*2048; lane l holds its 32 B at offset l*32 -- exactly
//   the mfma_scale 16x16x128 operand order. Frag load = contiguous 2 KB/wave.
// ---------------------------------------------------------------------------

// Kernel 1: per-row L2 normalize fp32 -> fp8 e4m3 into tiled layout;
// sq[row]=||n||^2; zero counter.
__global__ __launch_bounds__(256) void normalize_rows(
    const float* __restrict__ x, unsigned char* __restrict__ nf8,
    float* __restrict__ sq, unsigned int* __restrict__ counter)
{
    if (blockIdx.x == 0 && threadIdx.x == 0) { *counter = 0u; }
    int row = blockIdx.x * 4 + (threadIdx.x >> 6);
    int l = threadIdx.x & 63;
    const float4* xr = (const float4*)(x + (size_t)row * DDIM);
    float4 f0 = xr[l];
    float4 f1 = xr[l + 64];
    float s = f0.x*f0.x + f0.y*f0.y + f0.z*f0.z + f0.w*f0.w
            + f1.x*f1.x + f1.y*f1.y + f1.z*f1.z + f1.w*f1.w;
    #pragma unroll
    for (int m = 1; m < 64; m <<= 1) s += __shfl_xor(s, m);
    float rn = rsqrtf(s);
    int pk0 = __builtin_amdgcn_cvt_pk_fp8_f32(f0.x * rn, f0.y * rn, 0, false);
    pk0     = __builtin_amdgcn_cvt_pk_fp8_f32(f0.z * rn, f0.w * rn, pk0, true);
    int pk1 = __builtin_amdgcn_cvt_pk_fp8_f32(f1.x * rn, f1.y * rn, 0, false);
    pk1     = __builtin_amdgcn_cvt_pk_fp8_f32(f1.z * rn, f1.w * rn, pk1, true);
    // tiled scatter: pk0 covers k=[4l,4l+4), pk1 covers k=[4l+256,4l+260)
    size_t base = (size_t)(row >> 4) * 4 * 2048;
    int within = ((row & 15) + ((l >> 3) & 3) * 16) * 32 + (l & 7) * 4;
    int kc0 = l >> 5;          // k=4l       -> kc in {0,1}
    int kc1 = (l >> 5) + 2;    // k=4l+256   -> kc in {2,3}
    *(int*)(nf8 + base + (size_t)kc0 * 2048 + within) = pk0;
    *(int*)(nf8 + base + (size_t)kc1 * 2048 + within) = pk1;
    if (l == 0) sq[row] = s * rn * rn;
}

// unit u -> (ti, tj): ti in [0,128) row-panel of 64 rows; tj col-panel of 128
// cols with tj >= ti/2 (units not entirely below the diagonal).
// Pairing m = ti>>1: cum(m) = m*(129-m), span 2*(64-m).
__device__ __forceinline__ void decode_unit(int u, int& ti, int& tj) {
    int m = (int)((129.0f - sqrtf(16641.0f - 4.0f * (float)u)) * 0.5f);
    if (m > 63) m = 63;
    while (m < 63 && (m + 1) * (129 - (m + 1)) <= u) ++m;
    while (m > 0 && m * (129 - m) > u) --m;
    int rem = u - m * (129 - m);
    int span = 64 - m;
    if (rem < span) { ti = 2 * m;     tj = m + rem; }
    else            { ti = 2 * m + 1; tj = m + rem - span; }
}

// Kernel 2: BARRIER-FREE drifting waves. One 64x128 unit per 4-wave block;
// wave w owns 64 rows x 32 cols (acc = 8 f32x4 = 32 regs). No LDS staging,
// no s_barrier anywhere in the compute path -- every previous barrier-synced
// structure (r5-r11) pinned per-CU throughput at 41-47 cyc/MFMA vs the
// 8.6-cyc pipe floor regardless of occupancy/vmcnt/tile-size (the m233-class
// lockstep overhead). Here each wave register-double-buffers its operands
// (af[4]+bf[2] even/odd = 96 regs; total ~160 << 256 cap, vs r7's ~240 that
// spilled), prefetches chunk c+1 before chunk c's MFMAs (sched_barrier(0)
// pins issue order; compiler's counted vmcnt leaves them in flight), and the
// 8 independent waves/CU drift freely so per-wave L2 waits overlap.
// 4160 units / 512 resident blocks = 8.125 -> ~11% tail (vs 23-48% before).
__global__ __launch_bounds__(256, 2) void gram_hinge(
    const unsigned char* __restrict__ nf8, const float* __restrict__ sq,
    const int* __restrict__ y, double* __restrict__ part,
    unsigned int* __restrict__ counter, float* __restrict__ out)
{
    __shared__ float wpart[4];
    __shared__ double dpart[4];
    __shared__ int is_last;

    int tid = threadIdx.x;
    int w = tid >> 6, l = tid & 63;
    int lr = l & 15, q = l >> 4;

    int ti, tj;
    decode_unit(blockIdx.x, ti, tj);

    // per-lane frag base pointers: A row-frags ti*4+mi, B col-frags tj*8+w*2+ni
    const unsigned char* pA = nf8 + ((size_t)(ti * 4) * 4) * 2048 + l * 32;
    const unsigned char* pB = nf8 + ((size_t)((tj * 8 + w * 2) * 4)) * 2048 + l * 32;
    // frag (f, chunk kc) at p + f*8192 + kc*2048

    float acc0 = 0.f, acc1 = 0.f;
    f32x4 accv[4][2] = {};
    i32x8 afe[4], afo[4], bfe[2], bfo[2];

    // prologue: chunk 0 -> even buffers (6 x 2KB frag loads)
    #pragma unroll
    for (int mi = 0; mi < 4; ++mi) afe[mi] = *(const i32x8*)(pA + mi * 8192);
    #pragma unroll
    for (int ni = 0; ni < 2; ++ni) bfe[ni] = *(const i32x8*)(pB + ni * 8192);

    #pragma unroll 1
    for (int cc = 0; cc < 2; ++cc) {
        int ko = 2 * cc + 1;                   // odd chunk index: 1, 3
        // issue odd-chunk loads (stay in flight through even MFMAs)
        #pragma unroll
        for (int mi = 0; mi < 4; ++mi)
            afo[mi] = *(const i32x8*)(pA + mi * 8192 + ko * 2048);
        #pragma unroll
        for (int ni = 0; ni < 2; ++ni)
            bfo[ni] = *(const i32x8*)(pB + ni * 8192 + ko * 2048);
        __builtin_amdgcn_sched_barrier(0);     // loads issued before MFMAs
        __builtin_amdgcn_s_setprio(1);
        #pragma unroll
        for (int mi = 0; mi < 4; ++mi)
            #pragma unroll
            for (int ni = 0; ni < 2; ++ni)
                accv[mi][ni] = __builtin_amdgcn_mfma_scale_f32_16x16x128_f8f6f4(
                    afe[mi], bfe[ni], accv[mi][ni],
                    0, 0, 0, 0x7F7F7F7F, 0, 0x7F7F7F7F);
        __builtin_amdgcn_s_setprio(0);
        // issue next even chunk (kc=2) loads -- only mid-unit
        if (cc == 0) {
            #pragma unroll
            for (int mi = 0; mi < 4; ++mi)
                afe[mi] = *(const i32x8*)(pA + mi * 8192 + 2 * 2048);
            #pragma unroll
            for (int ni = 0; ni < 2; ++ni)
                bfe[ni] = *(const i32x8*)(pB + ni * 8192 + 2 * 2048);
        }
        __builtin_amdgcn_sched_barrier(0);     // loads issued before MFMAs
        __builtin_amdgcn_s_setprio(1);
        #pragma unroll
        for (int mi = 0; mi < 4; ++mi)
            #pragma unroll
            for (int ni = 0; ni < 2; ++ni)
                accv[mi][ni] = __builtin_amdgcn_mfma_scale_f32_16x16x128_f8f6f4(
                    afo[mi], bfo[ni], accv[mi][ni],
                    0, 0, 0, 0x7F7F7F7F, 0, 0x7F7F7F7F);
        __builtin_amdgcn_s_setprio(0);
    }

    // ---- epilogue (C/D layout: col=lane&15 -> j, row=q*4+reg -> i) ----
    // wave patch: rows [ti*64, +64), cols [tj*128 + w*32, +32)
    {
        int jb = tj * 128 + w * 32 + lr;
        float sqj[2]; int yj[2];
        #pragma unroll
        for (int ni = 0; ni < 2; ++ni) {
            sqj[ni] = sq[jb + ni * 16];
            yj[ni]  = y[jb + ni * 16];
        }
        int d = tj * 128 + w * 32 - ti * 64;   // col-start minus row-start
        if (d > -32) {                          // not entirely below diagonal
            if (d >= 64) {
                // fully above diagonal
                #pragma unroll
                for (int mi = 0; mi < 4; ++mi) {
                    #pragma unroll
                    for (int r = 0; r < 4; ++r) {
                        int ia = ti * 64 + mi * 16 + q * 4 + r;
                        float ci = THETA - sq[ia];
                        int yi = y[ia];
                        float h0 = fmaxf(fmaf(2.f, accv[mi][0][r], ci - sqj[0]), 0.f);
                        acc0 += (yi == yj[0]) ? h0 : -h0;
                        float h1 = fmaxf(fmaf(2.f, accv[mi][1][r], ci - sqj[1]), 0.f);
                        acc1 += (yi == yj[1]) ? h1 : -h1;
                    }
                }
            } else {
                // straddling: keep element iff global j >= global i
                #pragma unroll
                for (int mi = 0; mi < 4; ++mi) {
                    #pragma unroll
                    for (int r = 0; r < 4; ++r) {
                        int ig = ti * 64 + mi * 16 + q * 4 + r;
                        float ci = THETA - sq[ig];
                        int yi = y[ig];
                        #pragma unroll
                        for (int ni = 0; ni < 2; ++ni) {
                            float h = fmaxf(fmaf(2.f, accv[mi][ni][r], ci - sqj[ni]), 0.f);
                            float sh = (yi == yj[ni]) ? h : -h;
                            if (jb + ni * 16 >= ig) acc0 += sh;
                        }
                    }
                }
            }
        }
    }

    float local = acc0 + acc1;
    #pragma unroll
    for (int off = 32; off > 0; off >>= 1) local += __shfl_down(local, off);
    if (l == 0) wpart[w] = local;
    __syncthreads();
    if (tid == 0) {
        double ssum = (double)wpart[0] + (double)wpart[1]
                    + (double)wpart[2] + (double)wpart[3];
        __hip_atomic_store(&part[blockIdx.x], ssum, __ATOMIC_RELEASE, __HIP_MEMORY_SCOPE_AGENT);
        unsigned int ticket = __hip_atomic_fetch_add(
            counter, 1u, __ATOMIC_ACQ_REL, __HIP_MEMORY_SCOPE_AGENT);
        is_last = (ticket == NUNITS - 1) ? 1 : 0;
    }
    __syncthreads();
    if (is_last) {
        double s = 0.0;
        for (int i = tid; i < NUNITS; i += 256)
            s += __hip_atomic_load(&part[i], __ATOMIC_ACQUIRE, __HIP_MEMORY_SCOPE_AGENT);
        #pragma unroll
        for (int off = 32; off > 0; off >>= 1) s += __shfl_down(s, off);
        if (l == 0) dpart[w] = s;
        __syncthreads();
        if (tid == 0) {
            // add the analytically-known XI term: XI * #upper-tri pairs
            double total = (dpart[0] + dpart[1] + dpart[2] + dpart[3])
                         + (double)XI * NPAIRS_UP;
            const double m = 1.0 / ((double)BDIM * (double)BDIM - (double)BDIM);
            out[0] = (float)(total * m);
        }
    }
}

extern "C" void kernel_launch(void* const* d_in, const int* in_sizes, int n_in,
                              void* d_out, int out_size, void* d_ws, size_t ws_size,
                              hipStream_t stream) {
    const float* x = (const float*)d_in[0];
    const int* y = (const int*)d_in[1];
    float* out = (float*)d_out;

    unsigned char* nf8 = (unsigned char*)d_ws;                          // 4 MB fp8 (tiled)
    char* p = (char*)d_ws + (size_t)BDIM * DDIM;
    float* sq = (float*)p;                                              // 32 KB
    unsigned int* counter = (unsigned int*)(p + (size_t)BDIM * 4);
    double* part = (double*)(p + (size_t)BDIM * 4 + 64);                // NUNITS doubles

    normalize_rows<<<BDIM / 4, 256, 0, stream>>>(x, nf8, sq, counter);
    gram_hinge<<<NUNITS, 256, 0, stream>>>(nf8, sq, y, part, counter, out);
}

// Round 14
// 106.986 us; speedup vs baseline: 2.0407x; 2.0407x over previous
//
#include <hip/hip_runtime.h>
#include <cstdint>
#include <cstddef>

#define THETA 1.2f
#define XI 0.3f
#define BDIM 8192
#define DDIM 512
#define NPANEL 32          // 32 panels of 256 rows
#define NUNITS 528         // 32*33/2 upper-tri 256x256 units
#define GRID 256           // 1 block/CU (128 KB LDS); 2-3 units per block
// upper-triangle-with-diagonal pair count: B*(B+1)/2
#define NPAIRS_UP (((double)BDIM * (double)(BDIM + 1)) * 0.5)

typedef float f32x4 __attribute__((ext_vector_type(4)));
typedef int i32x8 __attribute__((ext_vector_type(8)));

// ---------------------------------------------------------------------------
// Fragment-major ("tiled") fp8 layout (verified r6-r13):
//   frag F = (row/16)*4 + (kbyte/128)   -- 16 rows x 128 B of K = one MFMA frag
//   blob of 2048 B at F*2048; lane l holds its 32 B at offset l*32 -- exactly
//   the mfma_scale 16x16x128 operand order.
// ---------------------------------------------------------------------------

// Kernel 1: per-row L2 normalize fp32 -> fp8 e4m3 into tiled layout;
// sq[row]=||n||^2; zero counter.
__global__ __launch_bounds__(256) void normalize_rows(
    const float* __restrict__ x, unsigned char* __restrict__ nf8,
    float* __restrict__ sq, unsigned int* __restrict__ counter)
{
    if (blockIdx.x == 0 && threadIdx.x == 0) { *counter = 0u; }
    int row = blockIdx.x * 4 + (threadIdx.x >> 6);
    int l = threadIdx.x & 63;
    const float4* xr = (const float4*)(x + (size_t)row * DDIM);
    float4 f0 = xr[l];
    float4 f1 = xr[l + 64];
    float s = f0.x*f0.x + f0.y*f0.y + f0.z*f0.z + f0.w*f0.w
            + f1.x*f1.x + f1.y*f1.y + f1.z*f1.z + f1.w*f1.w;
    #pragma unroll
    for (int m = 1; m < 64; m <<= 1) s += __shfl_xor(s, m);
    float rn = rsqrtf(s);
    int pk0 = __builtin_amdgcn_cvt_pk_fp8_f32(f0.x * rn, f0.y * rn, 0, false);
    pk0     = __builtin_amdgcn_cvt_pk_fp8_f32(f0.z * rn, f0.w * rn, pk0, true);
    int pk1 = __builtin_amdgcn_cvt_pk_fp8_f32(f1.x * rn, f1.y * rn, 0, false);
    pk1     = __builtin_amdgcn_cvt_pk_fp8_f32(f1.z * rn, f1.w * rn, pk1, true);
    // tiled scatter: pk0 covers k=[4l,4l+4), pk1 covers k=[4l+256,4l+260)
    size_t base = (size_t)(row >> 4) * 4 * 2048;
    int within = ((row & 15) + ((l >> 3) & 3) * 16) * 32 + (l & 7) * 4;
    int kc0 = l >> 5;          // k=4l       -> kc in {0,1}
    int kc1 = (l >> 5) + 2;    // k=4l+256   -> kc in {2,3}
    *(int*)(nf8 + base + (size_t)kc0 * 2048 + within) = pk0;
    *(int*)(nf8 + base + (size_t)kc1 * 2048 + within) = pk1;
    if (l == 0) sq[row] = s * rn * rn;
}

// unit u -> (ti, tj), ti<=tj in [0,32): cum(t) = t*(65-t)/2
__device__ __forceinline__ void decode_unit(int u, int& ti, int& tj) {
    int t = (int)((65.0f - sqrtf(4225.0f - 8.0f * (float)u)) * 0.5f);
    if (t < 0) t = 0;
    if (t > 31) t = 31;
    while (t < 31 && (t + 1) * (65 - (t + 1)) / 2 <= u) ++t;
    while (t > 0 && t * (65 - t) / 2 > u) --t;
    ti = t;
    tj = t + (u - t * (65 - t) / 2);
}

// Kernel 2: 256x256 units, 8 waves (2x4), per-wave 128x64 output (acc=128
// regs). BOTH operands LDS-staged (A 32KB + B 32KB per chunk, dbuf 128 KB)
// via global_load_lds; r8's proven counted-vmcnt two-barrier pipeline,
// carried across units. Rationale (r5-r13 ledger): every 128-tile variant
// pinned at 41-47 cyc/MFMA per CU regardless of occupancy/vmcnt/
// MFMA-per-barrier/barrier-free -- the fixed costs are per-TILE and
// L2-traffic-per-FLOP bound. 256^2 gives 4x MFMA per barrier-pair
// (256/chunk/CU: ~550 cyc/SIMD MFMA vs ~2000 cyc LDS pipe -> LDS becomes
// the binding pipe) and halves L2 traffic per output. Regs: acc 128 +
// bf 32 + af 8 + addr ~40 ~= 210 < 256 cap at (512,2) -- no spill by
// construction (r9 lesson: never cap below footprint).
// vmcnt(8): per stage a wave issues 4 A-DMA + 4 B-DMA.
__global__ __launch_bounds__(512, 2) void gram_hinge(
    const unsigned char* __restrict__ nf8, const float* __restrict__ sq,
    const int* __restrict__ y, double* __restrict__ part,
    unsigned int* __restrict__ counter, float* __restrict__ out)
{
    __shared__ unsigned char As[2][32768];   // 64 KB: A chunk frags, dbuf
    __shared__ unsigned char Bs[2][32768];   // 64 KB: B chunk frags, dbuf
    __shared__ float wpart[8];
    __shared__ double dpart[8];
    __shared__ int is_last;

    int tid = threadIdx.x;
    int w = tid >> 6, l = tid & 63;
    int wr = w >> 2, wc = w & 3;      // 2x4 wave grid: 128-row x 64-col patch
    int lr = l & 15, q = l >> 4;

    // stage one chunk (A: 16 frags = 32 KB, B: same) -- 4+4 x 1 KB DMA/wave
    auto stage = [&](unsigned char* dA, unsigned char* dB,
                     int pti, int ptj, int kc) {
        #pragma unroll
        for (int i = 0; i < 4; ++i) {
            int t = w * 4 + i;               // 0..31
            int rf = t >> 1, half = t & 1;   // frag 0..15, half 0..1
            const unsigned char* sA = nf8
                + ((size_t)((pti * 16 + rf) * 4 + kc)) * 2048 + half * 1024 + l * 16;
            const unsigned char* sB = nf8
                + ((size_t)((ptj * 16 + rf) * 4 + kc)) * 2048 + half * 1024 + l * 16;
            __builtin_amdgcn_global_load_lds(
                (const __attribute__((address_space(1))) void*)sA,
                (__attribute__((address_space(3))) void*)(dA + t * 1024), 16, 0, 0);
            __builtin_amdgcn_global_load_lds(
                (const __attribute__((address_space(1))) void*)sB,
                (__attribute__((address_space(3))) void*)(dB + t * 1024), 16, 0, 0);
        }
    };

    float acc0 = 0.f, acc1 = 0.f, acc2 = 0.f, acc3 = 0.f;

    int u = blockIdx.x;
    int ti, tj;
    decode_unit(u, ti, tj);

    // pipeline prologue: unit-0 chunk-0
    stage(As[0], Bs[0], ti, tj, 0);

    while (u < NUNITS) {
        int u_next = u + GRID;
        bool have_next = (u_next < NUNITS);
        int ti_n = 0, tj_n = 0;
        if (have_next) decode_unit(u_next, ti_n, tj_n);

        f32x4 accv[8][4] = {};

        #pragma unroll 1
        for (int cc = 0; cc < 2; ++cc) {
            // ===== even chunk e = 2cc (operands in As[0]/Bs[0]) =====
            stage(As[1], Bs[1], ti, tj, 2 * cc + 1);
            asm volatile("s_waitcnt vmcnt(8)" ::: "memory"); // stage(e) landed
            asm volatile("s_barrier" ::: "memory");
            {
                i32x8 bf[4];
                #pragma unroll
                for (int ni = 0; ni < 4; ++ni)
                    bf[ni] = *(const i32x8*)(Bs[0] + (wc * 4 + ni) * 2048 + l * 32);
                __builtin_amdgcn_s_setprio(1);
                #pragma unroll
                for (int mi = 0; mi < 8; ++mi) {
                    i32x8 af = *(const i32x8*)(As[0] + (wr * 8 + mi) * 2048 + l * 32);
                    #pragma unroll
                    for (int ni = 0; ni < 4; ++ni)
                        accv[mi][ni] = __builtin_amdgcn_mfma_scale_f32_16x16x128_f8f6f4(
                            af, bf[ni], accv[mi][ni],
                            0, 0, 0, 0x7F7F7F7F, 0, 0x7F7F7F7F);
                }
                __builtin_amdgcn_s_setprio(0);
            }
            asm volatile("s_barrier" ::: "memory");   // buf0 readers done

            // ===== odd chunk o = 2cc+1 (operands in As[1]/Bs[1]) =====
            bool more = (cc == 0) || have_next;
            int nti = (cc == 0) ? ti : ti_n;
            int ntj = (cc == 0) ? tj : tj_n;
            int nc  = (cc == 0) ? 2 : 0;
            if (more) {
                stage(As[0], Bs[0], nti, ntj, nc);
                asm volatile("s_waitcnt vmcnt(8)" ::: "memory"); // stage(o) landed
            } else {
                asm volatile("s_waitcnt vmcnt(0)" ::: "memory");  // end of work
            }
            asm volatile("s_barrier" ::: "memory");
            {
                i32x8 bf[4];
                #pragma unroll
                for (int ni = 0; ni < 4; ++ni)
                    bf[ni] = *(const i32x8*)(Bs[1] + (wc * 4 + ni) * 2048 + l * 32);
                __builtin_amdgcn_s_setprio(1);
                #pragma unroll
                for (int mi = 0; mi < 8; ++mi) {
                    i32x8 af = *(const i32x8*)(As[1] + (wr * 8 + mi) * 2048 + l * 32);
                    #pragma unroll
                    for (int ni = 0; ni < 4; ++ni)
                        accv[mi][ni] = __builtin_amdgcn_mfma_scale_f32_16x16x128_f8f6f4(
                            af, bf[ni], accv[mi][ni],
                            0, 0, 0, 0x7F7F7F7F, 0, 0x7F7F7F7F);
                }
                __builtin_amdgcn_s_setprio(0);
            }
            asm volatile("s_barrier" ::: "memory");   // buf1 readers done
        }

        // ---- per-unit epilogue (C/D layout: col=lane&15 -> j, row=q*4+reg -> i)
        // wave patch: rows ti*256 + wr*128 + [0,128), cols tj*256 + wc*64 + [0,64)
        // overlaps the in-flight next-unit chunk-0 DMAs.
        {
            int jb = tj * 256 + wc * 64 + lr;
            float sqj[4]; int yj[4];
            #pragma unroll
            for (int ni = 0; ni < 4; ++ni) {
                sqj[ni] = sq[jb + ni * 16];
                yj[ni]  = y[jb + ni * 16];
            }
            bool skip = (ti == tj) && (wr == 1) && (wc < 2);
            bool full = (ti != tj) || ((wr == 0) && (wc >= 2));
            if (!skip) {
                if (full) {
                    #pragma unroll
                    for (int mi = 0; mi < 8; ++mi) {
                        #pragma unroll
                        for (int r = 0; r < 4; ++r) {
                            int ia = ti * 256 + wr * 128 + mi * 16 + q * 4 + r;
                            float ci = THETA - sq[ia];
                            int yi = y[ia];
                            float h0 = fmaxf(fmaf(2.f, accv[mi][0][r], ci - sqj[0]), 0.f);
                            acc0 += (yi == yj[0]) ? h0 : -h0;
                            float h1 = fmaxf(fmaf(2.f, accv[mi][1][r], ci - sqj[1]), 0.f);
                            acc1 += (yi == yj[1]) ? h1 : -h1;
                            float h2 = fmaxf(fmaf(2.f, accv[mi][2][r], ci - sqj[2]), 0.f);
                            acc2 += (yi == yj[2]) ? h2 : -h2;
                            float h3 = fmaxf(fmaf(2.f, accv[mi][3][r], ci - sqj[3]), 0.f);
                            acc3 += (yi == yj[3]) ? h3 : -h3;
                        }
                    }
                } else {
                    // straddling diag quadrant: keep element iff global j >= i
                    #pragma unroll
                    for (int mi = 0; mi < 8; ++mi) {
                        #pragma unroll
                        for (int r = 0; r < 4; ++r) {
                            int ia = ti * 256 + wr * 128 + mi * 16 + q * 4 + r;
                            float ci = THETA - sq[ia];
                            int yi = y[ia];
                            #pragma unroll
                            for (int ni = 0; ni < 4; ++ni) {
                                float h = fmaxf(fmaf(2.f, accv[mi][ni][r], ci - sqj[ni]), 0.f);
                                float sh = (yi == yj[ni]) ? h : -h;
                                if (jb + ni * 16 >= ia) acc0 += sh;
                            }
                        }
                    }
                }
            }
        }

        u = u_next; ti = ti_n; tj = tj_n;
    }

    float local = (acc0 + acc1) + (acc2 + acc3);
    #pragma unroll
    for (int off = 32; off > 0; off >>= 1) local += __shfl_down(local, off);
    if (l == 0) wpart[w] = local;
    __syncthreads();
    if (tid == 0) {
        double ssum = 0.0;
        #pragma unroll
        for (int i = 0; i < 8; ++i) ssum += (double)wpart[i];
        __hip_atomic_store(&part[blockIdx.x], ssum, __ATOMIC_RELEASE, __HIP_MEMORY_SCOPE_AGENT);
        unsigned int ticket = __hip_atomic_fetch_add(
            counter, 1u, __ATOMIC_ACQ_REL, __HIP_MEMORY_SCOPE_AGENT);
        is_last = (ticket == GRID - 1) ? 1 : 0;
    }
    __syncthreads();
    if (is_last) {
        double s = 0.0;
        for (int i = tid; i < GRID; i += 512)
            s += __hip_atomic_load(&part[i], __ATOMIC_ACQUIRE, __HIP_MEMORY_SCOPE_AGENT);
        #pragma unroll
        for (int off = 32; off > 0; off >>= 1) s += __shfl_down(s, off);
        if (l == 0) dpart[w] = s;
        __syncthreads();
        if (tid == 0) {
            double t8 = 0.0;
            #pragma unroll
            for (int i = 0; i < 8; ++i) t8 += dpart[i];
            // add the analytically-known XI term: XI * #upper-tri pairs
            double total = t8 + (double)XI * NPAIRS_UP;
            const double m = 1.0 / ((double)BDIM * (double)BDIM - (double)BDIM);
            out[0] = (float)(total * m);
        }
    }
}

extern "C" void kernel_launch(void* const* d_in, const int* in_sizes, int n_in,
                              void* d_out, int out_size, void* d_ws, size_t ws_size,
                              hipStream_t stream) {
    const float* x = (const float*)d_in[0];
    const int* y = (const int*)d_in[1];
    float* out = (float*)d_out;

    unsigned char* nf8 = (unsigned char*)d_ws;                          // 4 MB fp8 (tiled)
    char* p = (char*)d_ws + (size_t)BDIM * DDIM;
    float* sq = (float*)p;                                              // 32 KB
    unsigned int* counter = (unsigned int*)(p + (size_t)BDIM * 4);
    double* part = (double*)(p + (size_t)BDIM * 4 + 64);                // GRID doubles

    normalize_rows<<<BDIM / 4, 256, 0, stream>>>(x, nf8, sq, counter);
    gram_hinge<<<GRID, 512, 0, stream>>>(nf8, sq, y, part, counter, out);
}